// Round 10
// baseline (798.129 us; speedup 1.0000x reference)
//
#include <hip/hip_runtime.h>
#include <hip/hip_bf16.h>
#include <cstdint>

// MultiHeadAttention w/ sparsemax: B=2, S=2048, D=1024, H=16, DK=64
#define S_LEN  2048
#define DMODEL 1024
#define NHEAD  16
#define M_ROWS 4096                       // B*S

typedef __attribute__((ext_vector_type(8))) short bf16x8;   // MFMA A/B frag (8 bf16)
typedef __attribute__((ext_vector_type(4))) float f32x4;    // MFMA C/D frag

__device__ __forceinline__ unsigned short f2bf(float f) {
    __hip_bfloat16 h = __float2bfloat16(f);
    return __builtin_bit_cast(unsigned short, h);
}
__device__ __forceinline__ float bf2f(unsigned short u) {
    return __builtin_bit_cast(float, (unsigned)u << 16);
}
__device__ __forceinline__ uint4 pack8(float4 a, float4 b) {
    uint4 u;
    u.x = ((unsigned)f2bf(a.y) << 16) | f2bf(a.x);
    u.y = ((unsigned)f2bf(a.w) << 16) | f2bf(a.z);
    u.z = ((unsigned)f2bf(b.y) << 16) | f2bf(b.x);
    u.w = ((unsigned)f2bf(b.w) << 16) | f2bf(b.z);
    return u;
}

// LDS-only barrier: drains lgkmcnt (LDS visibility) but NOT vmcnt, so global
// loads/stores in flight stay in flight across the barrier. __syncthreads would
// emit s_waitcnt vmcnt(0) and stall every wave on its prefetch/store queue.
__device__ __forceinline__ void lds_barrier() {
    asm volatile("s_waitcnt lgkmcnt(0)" ::: "memory");
    __builtin_amdgcn_s_barrier();
}

// ---------------------------------------------------------------- wave reduce
__device__ __forceinline__ float wave_sum64(float v) {
    v += __shfl_xor(v, 32, 64); v += __shfl_xor(v, 16, 64);
    v += __shfl_xor(v, 8, 64);  v += __shfl_xor(v, 4, 64);
    v += __shfl_xor(v, 2, 64);  v += __shfl_xor(v, 1, 64);
    return v;
}
__device__ __forceinline__ float wave_max64(float v) {
    v = fmaxf(v, __shfl_xor(v, 32, 64)); v = fmaxf(v, __shfl_xor(v, 16, 64));
    v = fmaxf(v, __shfl_xor(v, 8, 64));  v = fmaxf(v, __shfl_xor(v, 4, 64));
    v = fmaxf(v, __shfl_xor(v, 2, 64));  v = fmaxf(v, __shfl_xor(v, 1, 64));
    return v;
}
__device__ __forceinline__ int lanes_below(unsigned long long m) {
    return __builtin_amdgcn_mbcnt_hi((unsigned)(m >> 32),
           __builtin_amdgcn_mbcnt_lo((unsigned)m, 0));
}

// ------------------------------------- qkv: C = A@W^T + b (fp32 in, bf16 MFMA)
// Single-barrier double-buffered LDS. 1D grid with XCD swizzle: 96 consecutive
// swizzled ids per XCD = 3 W col-panels (1.5 MB) -> W stays L2-resident.
// Q output (which==0) pre-scaled by 0.125 (= 1/sqrt(DK)).
__global__ __launch_bounds__(256)
void qkv_gemm(const float* __restrict__ xq, const float* __restrict__ xk,
              const float* __restrict__ xv,
              const float* __restrict__ Wq, const float* __restrict__ Wk,
              const float* __restrict__ Wv,
              const float* __restrict__ bq, const float* __restrict__ bk,
              const float* __restrict__ bv,
              unsigned short* __restrict__ Q_bf, unsigned short* __restrict__ K_bf,
              unsigned short* __restrict__ V_bf) {
    // 768 blocks: swz = (id%8)*96 + id/8 (bijective, 768 = 8*96)
    const int id = blockIdx.x;
    const int swz = (id & 7) * 96 + (id >> 3);
    const int which = swz >> 8;                // /256
    const int rem = swz & 255;
    const int row0 = (rem & 31) * 128;
    const int col0 = (rem >> 5) * 128;

    const float* A    = (which == 0) ? xq : (which == 1) ? xk : xv;
    const float* W    = (which == 0) ? Wq : (which == 1) ? Wk : Wv;
    const float* bias = (which == 0) ? bq : (which == 1) ? bk : bv;
    unsigned short* dst = (which == 0) ? Q_bf : (which == 1) ? K_bf : V_bf;
    const float qscale = (which == 0) ? 0.125f : 1.0f;

    __shared__ unsigned short SMEM[20480];    // 2 x (As 5120 + Bs 5120); 40 KB
    const int t = threadIdx.x;
    const int wid = t >> 6, lane = t & 63;
    const int wm = wid >> 1, wn = wid & 1;
    const int l = lane & 15, quad = lane >> 4;

    f32x4 acc[4][4];
#pragma unroll
    for (int i = 0; i < 4; ++i)
#pragma unroll
        for (int j = 0; j < 4; ++j) {
            float b_ = bias[col0 + wn * 64 + j * 16 + l];
            acc[i][j] = (f32x4){ b_, b_, b_, b_ };
        }

    uint4 ar[2], br[2];
    // prologue: load K-step 0
#pragma unroll
    for (int i = 0; i < 2; ++i) {
        const int c = t + i * 256, r = c >> 2, q = (c & 3) * 8;
        const float* ap = A + (size_t)(row0 + r) * DMODEL + q;
        const float* wp = W + (size_t)(col0 + r) * DMODEL + q;
        float4 a0 = *(const float4*)ap, a1 = *(const float4*)(ap + 4);
        float4 w0 = *(const float4*)wp, w1 = *(const float4*)(wp + 4);
        ar[i] = pack8(a0, a1);
        br[i] = pack8(w0, w1);
    }

    for (int k0 = 0; k0 < DMODEL; k0 += 32) {
        unsigned short* As = SMEM + ((k0 >> 5) & 1) * 10240;
        unsigned short* Bs = As + 5120;
#pragma unroll
        for (int i = 0; i < 2; ++i) {
            const int c = t + i * 256, r = c >> 2, q = (c & 3) * 8;
            *(uint4*)&As[r * 40 + q] = ar[i];
            *(uint4*)&Bs[r * 40 + q] = br[i];
        }
        lds_barrier();
        if (k0 + 32 < DMODEL) {                // issue next-step loads (overlap)
#pragma unroll
            for (int i = 0; i < 2; ++i) {
                const int c = t + i * 256, r = c >> 2, q = (c & 3) * 8;
                const float* ap = A + (size_t)(row0 + r) * DMODEL + k0 + 32 + q;
                const float* wp = W + (size_t)(col0 + r) * DMODEL + k0 + 32 + q;
                float4 a0 = *(const float4*)ap, a1 = *(const float4*)(ap + 4);
                float4 w0 = *(const float4*)wp, w1 = *(const float4*)(wp + 4);
                ar[i] = pack8(a0, a1);
                br[i] = pack8(w0, w1);
            }
        }
        bf16x8 a[4], b[4];
#pragma unroll
        for (int i = 0; i < 4; ++i)
            a[i] = *(const bf16x8*)&As[(wm * 64 + i * 16 + l) * 40 + quad * 8];
#pragma unroll
        for (int j = 0; j < 4; ++j)
            b[j] = *(const bf16x8*)&Bs[(wn * 64 + j * 16 + l) * 40 + quad * 8];
#pragma unroll
        for (int i = 0; i < 4; ++i)
#pragma unroll
            for (int j = 0; j < 4; ++j)
                acc[i][j] = __builtin_amdgcn_mfma_f32_16x16x32_bf16(a[i], b[j], acc[i][j], 0, 0, 0);
        // no 2nd barrier: next write targets the other buffer.
    }

    // ---- epilogue: acc -> LDS (bf16, stride 72) -> uint4 stores
    lds_barrier();
    unsigned short* Cs = SMEM;                // 128*72 = 9216 <= 20480
#pragma unroll 1
    for (int jh = 0; jh < 2; ++jh) {
        if (wn == jh) {
#pragma unroll
            for (int i = 0; i < 4; ++i)
#pragma unroll
                for (int j = 0; j < 4; ++j)
#pragma unroll
                    for (int r = 0; r < 4; ++r)
                        Cs[(wm * 64 + i * 16 + quad * 4 + r) * 72 + j * 16 + l] =
                            f2bf(acc[i][j][r] * qscale);
        }
        lds_barrier();
#pragma unroll
        for (int it = 0; it < 4; ++it) {
            const int idx = t + it * 256;           // 0..1023
            const int row = idx >> 3, c8 = (idx & 7) * 8;
            *(uint4*)(dst + (size_t)(row0 + row) * DMODEL + col0 + jh * 64 + c8) =
                *(const uint4*)&Cs[row * 72 + c8];
        }
        lds_barrier();   // stores stay in flight (no vmcnt drain); Cs reads done
    }
}

// ------------------------- fused logits + sparsemax + sparse PV -------------------------
// v10 = v9 + (a) lds_barrier for the quarter/final barriers: the prefetched
// next-quarter K fragments are no longer drained at the barrier (vmcnt wait
// moves to their first MFMA use, one z-read phase later); (b) XCD-swizzled
// block ids: each XCD's L2 holds 4 heads' K+V slices (2 MB < 4 MB) instead of
// thrashing all 32 (16 MB) -> K-prefetch and V-gather latencies drop.
__global__ __launch_bounds__(1024, 4)
void attn_fused(const unsigned short* __restrict__ Q_bf,
                const unsigned short* __restrict__ K_bf,
                const unsigned short* __restrict__ V_bf,
                float* __restrict__ attn,
                unsigned short* __restrict__ AO_bf) {
    const int t = threadIdx.x;
    const int w = t >> 6, lane = t & 63;
    const int l = lane & 15, quad = lane >> 4;
    // 4096 blocks: swz = (id%8)*512 + id/8 (bijective, 4096 = 8*512)
    const int id = blockIdx.x;
    const int swz = (id & 7) * 512 + (id >> 3);
    const int bh = swz >> 7, b_ = bh >> 4, h = bh & 15;
    const int r0 = (swz & 127) * 16;

    __shared__ float TR[2][16][516];   // 66048 B ping-pong transpose (516: 2-way banks)
    uint2* List = (uint2*)&TR[0][0][0]; // aliased after transpose phase (64 KB used)

    // ---- Q fragments: 16 real rows r0+l
    const unsigned short* Qp =
        Q_bf + ((size_t)(b_ * S_LEN + r0 + l)) * DMODEL + h * 64 + quad * 8;
    const bf16x8 a0 = *(const bf16x8*)Qp;
    const bf16x8 a1 = *(const bf16x8*)(Qp + 32);

    // ---- K base: quarter q, tile ct -> row q*512 + w*32 + ct*16 + l
    const unsigned short* KB =
        K_bf + ((size_t)(b_ * S_LEN + w * 32 + l)) * DMODEL + h * 64 + quad * 8;

    float z[32];
    float m = -__builtin_inff();
    bf16x8 cb0[2], cb1[2], nb0[2], nb1[2];
#pragma unroll
    for (int ct = 0; ct < 2; ++ct) {           // prologue: quarter 0 frags
        const unsigned short* Kp = KB + (size_t)(ct * 16) * DMODEL;
        cb0[ct] = *(const bf16x8*)Kp;
        cb1[ct] = *(const bf16x8*)(Kp + 32);
    }
#pragma unroll
    for (int q = 0; q < 4; ++q) {
        if (q < 3) {                            // prefetch quarter q+1 (overlaps MFMA)
#pragma unroll
            for (int ct = 0; ct < 2; ++ct) {
                const unsigned short* Kp =
                    KB + (size_t)((q + 1) * 512 + ct * 16) * DMODEL;
                nb0[ct] = *(const bf16x8*)Kp;
                nb1[ct] = *(const bf16x8*)(Kp + 32);
            }
        }
#pragma unroll
        for (int ct = 0; ct < 2; ++ct) {
            f32x4 c = {};
            c = __builtin_amdgcn_mfma_f32_16x16x32_bf16(a0, cb0[ct], c, 0, 0, 0);
            c = __builtin_amdgcn_mfma_f32_16x16x32_bf16(a1, cb1[ct], c, 0, 0, 0);
#pragma unroll
            for (int r = 0; r < 4; ++r)        // Q pre-scaled by 1/8 in qkv
                TR[q & 1][quad * 4 + r][w * 32 + ct * 16 + l] = c[r];
        }
        lds_barrier();                          // prefetch loads NOT drained here
#pragma unroll
        for (int j = 0; j < 8; ++j) {
            z[q * 8 + j] = TR[q & 1][w][j * 64 + lane];
            m = fmaxf(m, z[q * 8 + j]);
        }
        if (q < 3) {
#pragma unroll
            for (int ct = 0; ct < 2; ++ct) { cb0[ct] = nb0[ct]; cb1[ct] = nb1[ct]; }
        }
    }
    lds_barrier();                              // transpose done -> List may alias

    // ---- row max; Newton iter 1 (full scan) -> tau1 (valid lower bound)
    m = wave_max64(m);
    float tau = m - 1.0f;
    {
        float ss = 0.0f; int kk = 0;
#pragma unroll
        for (int j = 0; j < 32; ++j) {
            const bool c = z[j] > tau;
            kk += (int)__popcll(__ballot(c));
            ss += c ? z[j] : 0.0f;
        }
        ss = wave_sum64(ss);
        tau = (ss - 1.0f) / (float)kk;          // tau1 <= tau*
    }

    // ---- candidate compaction: (col, z) with z > tau1
    uint2* list = List + w * 512;
    int cnt = 0;
#pragma unroll
    for (int jj = 0; jj < 32; ++jj) {
        const float zv = z[jj];
        const unsigned long long mk = __ballot(zv > tau);
        if (zv > tau) {
            const int pos = cnt + lanes_below(mk);
            if (pos < 512)
                list[pos] = (uint2){ (unsigned)((jj >> 3) * 512 + (jj & 7) * 64 + lane),
                                     __builtin_bit_cast(unsigned, zv) };
        }
        cnt += (int)__popcll(mk);
    }

    int scnt = 0;
    if (cnt <= 256) {
        const float NEG = -__builtin_inff();
        const uint2 E0 = list[lane];
        const uint2 E1 = list[64 + lane];
        const uint2 E2 = list[128 + lane];
        const uint2 E3 = list[192 + lane];
        const float zc0 = (lane < cnt)       ? __builtin_bit_cast(float, E0.y) : NEG;
        const float zc1 = (64 + lane < cnt)  ? __builtin_bit_cast(float, E1.y) : NEG;
        const float zc2 = (128 + lane < cnt) ? __builtin_bit_cast(float, E2.y) : NEG;
        const float zc3 = (192 + lane < cnt) ? __builtin_bit_cast(float, E3.y) : NEG;
#pragma unroll 1
        for (int it = 0; it < 12; ++it) {
            float ss = 0.0f; int kk = 0;
            kk += (int)__popcll(__ballot(zc0 > tau)); ss += (zc0 > tau) ? zc0 : 0.0f;
            kk += (int)__popcll(__ballot(zc1 > tau)); ss += (zc1 > tau) ? zc1 : 0.0f;
            kk += (int)__popcll(__ballot(zc2 > tau)); ss += (zc2 > tau) ? zc2 : 0.0f;
            kk += (int)__popcll(__ballot(zc3 > tau)); ss += (zc3 > tau) ? zc3 : 0.0f;
            ss = wave_sum64(ss);
            const float tn = (ss - 1.0f) / (float)kk;
            if (tn == tau) break;               // support stabilized -> exact
            tau = tn;
        }
        // support re-compaction from registers: store (col, p = z - tau)
        unsigned long long mk;
        mk = __ballot(zc0 > tau);
        if (zc0 > tau) list[scnt + lanes_below(mk)] =
            (uint2){ E0.x, __builtin_bit_cast(unsigned, zc0 - tau) };
        scnt += (int)__popcll(mk);
        mk = __ballot(zc1 > tau);
        if (zc1 > tau) list[scnt + lanes_below(mk)] =
            (uint2){ E1.x, __builtin_bit_cast(unsigned, zc1 - tau) };
        scnt += (int)__popcll(mk);
        mk = __ballot(zc2 > tau);
        if (zc2 > tau) list[scnt + lanes_below(mk)] =
            (uint2){ E2.x, __builtin_bit_cast(unsigned, zc2 - tau) };
        scnt += (int)__popcll(mk);
        mk = __ballot(zc3 > tau);
        if (zc3 > tau) list[scnt + lanes_below(mk)] =
            (uint2){ E3.x, __builtin_bit_cast(unsigned, zc3 - tau) };
        scnt += (int)__popcll(mk);
    } else {
        // fallback: continue full-scan Newton from tau1 (exactness preserved)
#pragma unroll 1
        for (int it = 0; it < 9; ++it) {
            float ss = 0.0f; int kk = 0;
#pragma unroll
            for (int j = 0; j < 32; ++j) {
                const bool c = z[j] > tau;
                kk += (int)__popcll(__ballot(c));
                ss += c ? z[j] : 0.0f;
            }
            ss = wave_sum64(ss);
            const float tn = (ss - 1.0f) / (float)kk;
            if (tn == tau) break;
            tau = tn;
        }
        // compact support from z, storing p
#pragma unroll
        for (int jj = 0; jj < 32; ++jj) {
            const float zv = z[jj];
            const unsigned long long mk = __ballot(zv > tau);
            if (zv > tau) {
                const int pos = scnt + lanes_below(mk);
                if (pos < 480)
                    list[pos] = (uint2){ (unsigned)((jj >> 3) * 512 + (jj & 7) * 64 + lane),
                                         __builtin_bit_cast(unsigned, zv - tau) };
            }
            scnt += (int)__popcll(mk);
        }
        if (scnt > 480) scnt = 480;
    }

    // ---- pad list with 32 zero entries (guard-free gather)
    if (lane < 32)
        list[scnt + lane] = (uint2){ 0u, 0u };  // p = 0 -> contributes nothing

    // ---- PREFETCH gather block 0: list entries + V loads issued BEFORE the
    //      attn store burst (loads older than stores in the vmcnt queue).
    const unsigned short* Vh = V_bf + ((size_t)b_ * S_LEN) * DMODEL + h * 64;
    const int sub = lane >> 3, dbase = (lane & 7) * 8;
    const uint2 e0 = list[sub];
    const uint2 e1 = list[sub + 8];
    const uint2 e2 = list[sub + 16];
    const uint2 e3 = list[sub + 24];
    const uint4 v0 = *(const uint4*)(Vh + (size_t)e0.x * DMODEL + dbase);
    const uint4 v1 = *(const uint4*)(Vh + (size_t)e1.x * DMODEL + dbase);
    const uint4 v2 = *(const uint4*)(Vh + (size_t)e2.x * DMODEL + dbase);
    const uint4 v3 = *(const uint4*)(Vh + (size_t)e3.x * DMODEL + dbase);

    // ---- attn store burst: p = max(z - tau, 0), coalesced nontemporal fp32
    float* ap = attn + (size_t)bh * S_LEN * S_LEN + (size_t)(r0 + w) * S_LEN;
#pragma unroll
    for (int jj = 0; jj < 32; ++jj) {
        const float pv = fmaxf(z[jj] - tau, 0.0f);
        __builtin_nontemporal_store(pv, ap + (jj >> 3) * 512 + (jj & 7) * 64 + lane);
    }

    // ---- FMA block 0 (waits only on the prefetched loads, not the stores)
    float acc8[8] = {};
    {
        const float p0 = __builtin_bit_cast(float, e0.y);
        const float p1 = __builtin_bit_cast(float, e1.y);
        const float p2 = __builtin_bit_cast(float, e2.y);
        const float p3 = __builtin_bit_cast(float, e3.y);
        acc8[0] += p0 * bf2f((unsigned short)(v0.x & 0xffff));
        acc8[1] += p0 * bf2f((unsigned short)(v0.x >> 16));
        acc8[2] += p0 * bf2f((unsigned short)(v0.y & 0xffff));
        acc8[3] += p0 * bf2f((unsigned short)(v0.y >> 16));
        acc8[4] += p0 * bf2f((unsigned short)(v0.z & 0xffff));
        acc8[5] += p0 * bf2f((unsigned short)(v0.z >> 16));
        acc8[6] += p0 * bf2f((unsigned short)(v0.w & 0xffff));
        acc8[7] += p0 * bf2f((unsigned short)(v0.w >> 16));
        acc8[0] += p1 * bf2f((unsigned short)(v1.x & 0xffff));
        acc8[1] += p1 * bf2f((unsigned short)(v1.x >> 16));
        acc8[2] += p1 * bf2f((unsigned short)(v1.y & 0xffff));
        acc8[3] += p1 * bf2f((unsigned short)(v1.y >> 16));
        acc8[4] += p1 * bf2f((unsigned short)(v1.z & 0xffff));
        acc8[5] += p1 * bf2f((unsigned short)(v1.z >> 16));
        acc8[6] += p1 * bf2f((unsigned short)(v1.w & 0xffff));
        acc8[7] += p1 * bf2f((unsigned short)(v1.w >> 16));
        acc8[0] += p2 * bf2f((unsigned short)(v2.x & 0xffff));
        acc8[1] += p2 * bf2f((unsigned short)(v2.x >> 16));
        acc8[2] += p2 * bf2f((unsigned short)(v2.y & 0xffff));
        acc8[3] += p2 * bf2f((unsigned short)(v2.y >> 16));
        acc8[4] += p2 * bf2f((unsigned short)(v2.z & 0xffff));
        acc8[5] += p2 * bf2f((unsigned short)(v2.z >> 16));
        acc8[6] += p2 * bf2f((unsigned short)(v2.w & 0xffff));
        acc8[7] += p2 * bf2f((unsigned short)(v2.w >> 16));
        acc8[0] += p3 * bf2f((unsigned short)(v3.x & 0xffff));
        acc8[1] += p3 * bf2f((unsigned short)(v3.x >> 16));
        acc8[2] += p3 * bf2f((unsigned short)(v3.y & 0xffff));
        acc8[3] += p3 * bf2f((unsigned short)(v3.y >> 16));
        acc8[4] += p3 * bf2f((unsigned short)(v3.z & 0xffff));
        acc8[5] += p3 * bf2f((unsigned short)(v3.z >> 16));
        acc8[6] += p3 * bf2f((unsigned short)(v3.w & 0xffff));
        acc8[7] += p3 * bf2f((unsigned short)(v3.w >> 16));
    }

    // ---- remaining gather blocks (rare: scnt > 32)
    const int gmax4 = (scnt + 31) >> 5;
#pragma unroll 1
    for (int g = 1; g < gmax4; ++g) {
        const int b0 = g * 32 + sub;
        const uint2 f0 = list[b0];
        const uint2 f1 = list[b0 + 8];
        const uint2 f2 = list[b0 + 16];
        const uint2 f3 = list[b0 + 24];
        const uint4 u0 = *(const uint4*)(Vh + (size_t)f0.x * DMODEL + dbase);
        const uint4 u1 = *(const uint4*)(Vh + (size_t)f1.x * DMODEL + dbase);
        const uint4 u2 = *(const uint4*)(Vh + (size_t)f2.x * DMODEL + dbase);
        const uint4 u3 = *(const uint4*)(Vh + (size_t)f3.x * DMODEL + dbase);
        const float p0 = __builtin_bit_cast(float, f0.y);
        const float p1 = __builtin_bit_cast(float, f1.y);
        const float p2 = __builtin_bit_cast(float, f2.y);
        const float p3 = __builtin_bit_cast(float, f3.y);
        acc8[0] += p0 * bf2f((unsigned short)(u0.x & 0xffff));
        acc8[1] += p0 * bf2f((unsigned short)(u0.x >> 16));
        acc8[2] += p0 * bf2f((unsigned short)(u0.y & 0xffff));
        acc8[3] += p0 * bf2f((unsigned short)(u0.y >> 16));
        acc8[4] += p0 * bf2f((unsigned short)(u0.z & 0xffff));
        acc8[5] += p0 * bf2f((unsigned short)(u0.z >> 16));
        acc8[6] += p0 * bf2f((unsigned short)(u0.w & 0xffff));
        acc8[7] += p0 * bf2f((unsigned short)(u0.w >> 16));
        acc8[0] += p1 * bf2f((unsigned short)(u1.x & 0xffff));
        acc8[1] += p1 * bf2f((unsigned short)(u1.x >> 16));
        acc8[2] += p1 * bf2f((unsigned short)(u1.y & 0xffff));
        acc8[3] += p1 * bf2f((unsigned short)(u1.y >> 16));
        acc8[4] += p1 * bf2f((unsigned short)(u1.z & 0xffff));
        acc8[5] += p1 * bf2f((unsigned short)(u1.z >> 16));
        acc8[6] += p1 * bf2f((unsigned short)(u1.w & 0xffff));
        acc8[7] += p1 * bf2f((unsigned short)(u1.w >> 16));
        acc8[0] += p2 * bf2f((unsigned short)(u2.x & 0xffff));
        acc8[1] += p2 * bf2f((unsigned short)(u2.x >> 16));
        acc8[2] += p2 * bf2f((unsigned short)(u2.y & 0xffff));
        acc8[3] += p2 * bf2f((unsigned short)(u2.y >> 16));
        acc8[4] += p2 * bf2f((unsigned short)(u2.z & 0xffff));
        acc8[5] += p2 * bf2f((unsigned short)(u2.z >> 16));
        acc8[6] += p2 * bf2f((unsigned short)(u2.w & 0xffff));
        acc8[7] += p2 * bf2f((unsigned short)(u2.w >> 16));
        acc8[0] += p3 * bf2f((unsigned short)(u3.x & 0xffff));
        acc8[1] += p3 * bf2f((unsigned short)(u3.x >> 16));
        acc8[2] += p3 * bf2f((unsigned short)(u3.y & 0xffff));
        acc8[3] += p3 * bf2f((unsigned short)(u3.y >> 16));
        acc8[4] += p3 * bf2f((unsigned short)(u3.z & 0xffff));
        acc8[5] += p3 * bf2f((unsigned short)(u3.z >> 16));
        acc8[6] += p3 * bf2f((unsigned short)(u3.w & 0xffff));
        acc8[7] += p3 * bf2f((unsigned short)(u3.w >> 16));
    }
    // reduce across the 8 subgroups (stride-8 butterfly)
#pragma unroll
    for (int d = 0; d < 8; ++d) {
        acc8[d] += __shfl_xor(acc8[d], 8, 64);
        acc8[d] += __shfl_xor(acc8[d], 16, 64);
        acc8[d] += __shfl_xor(acc8[d], 32, 64);
    }
    if (lane < 8) {
        union { unsigned short u[8]; uint4 v; } o;
#pragma unroll
        for (int d = 0; d < 8; ++d) o.u[d] = f2bf(acc8[d]);
        *(uint4*)(AO_bf + ((size_t)(b_ * S_LEN + r0 + w)) * DMODEL
                  + h * 64 + lane * 8) = o.v;
    }
}

// ---------------------- out = AO @ Wfc^T + bfc (bf16 A, fp32 W inline-cast)
// Single-barrier double-buffered LDS pipeline; XCD swizzle (1 W panel / XCD).
__global__ __launch_bounds__(256)
void fc_gemm(const unsigned short* __restrict__ AO_bf,
             const float* __restrict__ Wfc,
             const float* __restrict__ bfc, float* __restrict__ out) {
    // 256 blocks: swz = (id%8)*32 + id/8 (bijective, 256 = 8*32)
    const int id = blockIdx.x;
    const int swz = (id & 7) * 32 + (id >> 3);
    const int row0 = (swz & 31) * 128;
    const int col0 = (swz >> 5) * 128;

    __shared__ unsigned short SMEM[20480];    // 2 x (As 5120 + Bs 5120); 40 KB

    const int t = threadIdx.x;
    const int wid = t >> 6, lane = t & 63;
    const int wm = wid >> 1, wn = wid & 1;
    const int l = lane & 15, quad = lane >> 4;

    f32x4 acc[4][4];
#pragma unroll
    for (int i = 0; i < 4; ++i)
#pragma unroll
        for (int j = 0; j < 4; ++j) {
            float b_ = bfc[col0 + wn * 64 + j * 16 + l];
            acc[i][j] = (f32x4){ b_, b_, b_, b_ };
        }

    uint4 ar[2], br[2];
#pragma unroll
    for (int i = 0; i < 2; ++i) {
        const int c = t + i * 256, r = c >> 2, q = (c & 3) * 8;
        ar[i] = *(const uint4*)(AO_bf + (size_t)(row0 + r) * DMODEL + q);
        const float* wp = Wfc + (size_t)(col0 + r) * DMODEL + q;
        float4 w0 = *(const float4*)wp, w1 = *(const float4*)(wp + 4);
        br[i] = pack8(w0, w1);
    }

    for (int k0 = 0; k0 < DMODEL; k0 += 32) {
        unsigned short* As = SMEM + ((k0 >> 5) & 1) * 10240;
        unsigned short* Bs = As + 5120;
#pragma unroll
        for (int i = 0; i < 2; ++i) {
            const int c = t + i * 256, r = c >> 2, q = (c & 3) * 8;
            *(uint4*)&As[r * 40 + q] = ar[i];
            *(uint4*)&Bs[r * 40 + q] = br[i];
        }
        lds_barrier();
        if (k0 + 32 < DMODEL) {
#pragma unroll
            for (int i = 0; i < 2; ++i) {
                const int c = t + i * 256, r = c >> 2, q = (c & 3) * 8;
                ar[i] = *(const uint4*)(AO_bf + (size_t)(row0 + r) * DMODEL + k0 + 32 + q);
                const float* wp = Wfc + (size_t)(col0 + r) * DMODEL + k0 + 32 + q;
                float4 w0 = *(const float4*)wp, w1 = *(const float4*)(wp + 4);
                br[i] = pack8(w0, w1);
            }
        }
        bf16x8 a[4], b[4];
#pragma unroll
        for (int i = 0; i < 4; ++i)
            a[i] = *(const bf16x8*)&As[(wm * 64 + i * 16 + l) * 40 + quad * 8];
#pragma unroll
        for (int j = 0; j < 4; ++j)
            b[j] = *(const bf16x8*)&Bs[(wn * 64 + j * 16 + l) * 40 + quad * 8];
#pragma unroll
        for (int i = 0; i < 4; ++i)
#pragma unroll
            for (int j = 0; j < 4; ++j)
                acc[i][j] = __builtin_amdgcn_mfma_f32_16x16x32_bf16(a[i], b[j], acc[i][j], 0, 0, 0);
    }

#pragma unroll
    for (int i = 0; i < 4; ++i)
#pragma unroll
        for (int r = 0; r < 4; ++r) {
            const int m = row0 + wm * 64 + i * 16 + quad * 4 + r;
#pragma unroll
            for (int j = 0; j < 4; ++j) {
                const int n = col0 + wn * 64 + j * 16 + l;
                out[(size_t)m * DMODEL + n] = acc[i][j][r];
            }
        }
}

// ----------------------------------------------------------------------- launch
extern "C" void kernel_launch(void* const* d_in, const int* in_sizes, int n_in,
                              void* d_out, int out_size, void* d_ws, size_t ws_size,
                              hipStream_t stream) {
    const float* q   = (const float*)d_in[0];
    const float* k   = (const float*)d_in[1];
    const float* v   = (const float*)d_in[2];
    const float* Wq  = (const float*)d_in[3];
    const float* bq  = (const float*)d_in[4];
    const float* Wk  = (const float*)d_in[5];
    const float* bk  = (const float*)d_in[6];
    const float* Wv  = (const float*)d_in[7];
    const float* bv  = (const float*)d_in[8];
    const float* Wfc = (const float*)d_in[9];
    const float* bfc = (const float*)d_in[10];

    float* out  = (float*)d_out;                       // [B,S,D] fp32
    float* attn = out + (size_t)M_ROWS * DMODEL;       // [B,H,S,S] fp32

    // workspace: Q_bf [0,8M), K_bf [8,16M), V_bf [16,24M), AO_bf [24,32M)
    char* ws = (char*)d_ws;
    unsigned short* Q_bf  = (unsigned short*)ws;
    unsigned short* K_bf  = (unsigned short*)(ws + (8u << 20));
    unsigned short* V_bf  = (unsigned short*)(ws + (16u << 20));
    unsigned short* AO_bf = (unsigned short*)(ws + (24u << 20));

    qkv_gemm<<<768, 256, 0, stream>>>(q, k, v, Wq, Wk, Wv,
                                      bq, bk, bv, Q_bf, K_bf, V_bf);
    attn_fused<<<4096, 1024, 0, stream>>>(Q_bf, K_bf, V_bf, attn, AO_bf);
    fc_gemm<<<256, 256, 0, stream>>>(AO_bf, Wfc, bfc, out);
}